// Round 13
// baseline (1546.280 us; speedup 1.0000x reference)
//
#include <hip/hip_runtime.h>
#include <math.h>

// Capsule dynamic routing, MI355X. Round 16: fold kernels become "last block
// out" tails of their producer -- 6 dispatches -> 3, no grid barrier.
// R15 post-mortem: full-grid spin sync across 8 non-coherent XCD L2s is
// pathological (VALU 3.5%, 478MB FETCH of spin traffic). R16 uses the ticket
// pattern instead: each block stores its partial, __threadfence() (all
// threads), atomicAdd on a per-batch counter (64 RMWs/batch total, NO spin);
// the last block folds that batch. Fold loop order fixed -> deterministic.
// Main bodies of iter0/route are byte-identical to R11 (best, 168.7us).
// Tails reuse dead LDS (Vs4/PlCs after ph2) -> occupancy unchanged.
// Chain: iter0(+fold0->V) -> route1(+fold1->V) -> route2(+fold2->squash->out).

#define BATCH 64
#define NN    2048
#define KD    128
#define JCAP  10
#define DCAP  16
#define JDIM  160
#define EPSQ  1e-7f
#define NT    64      // tiles of TROW rows ; NT*TROW == NN
#define TROW  32

// ws layout: unsigned cnt[256] @0 (1KB, memset'd each launch); then floats:
//   Sp[64][64][128] ; V[64][10][128] ; Gp[64][64][10][128]
#define WS_SP 256
#define WS_V  (WS_SP + BATCH * NT * KD)
#define WS_GP (WS_V + BATCH * JCAP * KD)

__device__ __forceinline__ void gload16(const float* g, void* l) {
  __builtin_amdgcn_global_load_lds(
      (const __attribute__((address_space(1))) void*)g,
      (__attribute__((address_space(3))) void*)l, 16, 0, 0);
}

// ---- K1: per-tile colsum -> Sp ; last block per batch: fold0 -> V ----
__global__ __launch_bounds__(256) void f_iter0(const float* __restrict__ u,
                                               const float* __restrict__ W,
                                               float* __restrict__ ws) {
  const int b = blockIdx.y, tile = blockIdx.x, t = threadIdx.x;
  unsigned* cnt = (unsigned*)ws;
  float* Sp = ws + WS_SP;
  float* V  = ws + WS_V;
  __shared__ __align__(16) float4 red[256];
  __shared__ float g_s[KD];
  __shared__ float o_s[JDIM];
  __shared__ int isLast;
  const int c = t & 31, rg = t >> 5;        // 8 row-groups x 4 rows
  const float* p = u + (((size_t)(b * NN + tile * TROW + rg * 4)) << 7) + (c << 2);
  float4 a = make_float4(0.f, 0.f, 0.f, 0.f);
#pragma unroll
  for (int r = 0; r < 4; ++r) {
    const float4 w4 = *(const float4*)(p + ((size_t)r << 7));
    a.x += w4.x; a.y += w4.y; a.z += w4.z; a.w += w4.w;
  }
  red[t] = a;
  __syncthreads();
  if (t < 32) {
    float4 s4 = red[t];
#pragma unroll
    for (int g = 1; g < 8; ++g) {
      const float4 w4 = red[g * 32 + t];
      s4.x += w4.x; s4.y += w4.y; s4.z += w4.z; s4.w += w4.w;
    }
    *(float4*)&Sp[(size_t)(b * NT + tile) * KD + t * 4] = s4;
  }
  // ---- ticket: last block of batch b folds Sp -> V0 ----
  __threadfence();                       // each wave drains its own stores
  __syncthreads();
  if (t == 0) isLast = (atomicAdd(&cnt[b], 1u) == NT - 1);
  __syncthreads();
  if (!isLast) return;
  __threadfence();                       // acquire: see all blocks' Sp
  if (t < KD) {
    const float* q = Sp + (size_t)(b * NT) * KD + t;
    float s = 0.f;
#pragma unroll 8
    for (int tl = 0; tl < NT; ++tl) s += q[(size_t)tl * KD];
    g_s[t] = s * 0.1f;
  }
  __syncthreads();
  if (t < JDIM) {
    float a2 = 0.f;
#pragma unroll 8
    for (int k = 0; k < KD; ++k) a2 += g_s[k] * W[k * JDIM + t];
    o_s[t] = a2;
  }
  __syncthreads();
  if (t < KD) {
    const float* wp = W + t * JDIM;
#pragma unroll
    for (int j = 0; j < JCAP; ++j) {
      float a2 = 0.f;
#pragma unroll
      for (int d = 0; d < DCAP; ++d) a2 += wp[j * DCAP + d] * o_s[j * DCAP + d];
      V[((size_t)(b * JCAP) + j) * KD + t] = a2;
    }
  }
}

// ---- K2/K3: routing pass -> Gp ; last block per batch: fold -> {V | out} ----
__global__ __launch_bounds__(256) void f_route(const float* __restrict__ u,
                                               const float* __restrict__ W,
                                               float* __restrict__ ws,
                                               float* __restrict__ out,
                                               int pass) {
  const int b = blockIdx.y, tile = blockIdx.x, t = threadIdx.x;
  unsigned* cnt = (unsigned*)ws + 64 * pass;
  float* V  = ws + WS_V;
  float* Gp = ws + WS_GP;
  const int r0 = tile * TROW;
  __shared__ __align__(16) float4 u4[TROW * 32];        // 16 KB, XOR-swizzled
  __shared__ __align__(16) float4 Vs4[JCAP * 32];       // 5 KB; tail: gd[1280]
  __shared__ __align__(16) float PlCs[4 * JCAP * TROW]; // 5 KB; tail: o_s,sc
  __shared__ int isLast;

  // stage u tile (swizzled source, linear dest) + V (linear) via DMA
  {
    const float* ub = u + (((size_t)(b * NN + r0)) << 7);
    const int wbase = t & 192;                      // wave base within block
#pragma unroll
    for (int p = 0; p < 4; ++p) {
      const int s = p * 256 + t;
      const int r = s >> 5, csl = s & 31;
      const int c = csl ^ (r & 7);                  // involution
      gload16(ub + (((size_t)r) << 7) + (c << 2), &u4[p * 256 + wbase]);
    }
    const float* vb = V + (((size_t)(b * JCAP)) << 7);
    gload16(vb + (t << 2), &Vs4[wbase]);
    if (t < 64) gload16(vb + ((256 + t) << 2), &Vs4[256]);
  }
  __syncthreads();   // drains vmcnt

  // phase 1: logits. thread = (row r, k-eighth q8); V reads are broadcasts.
  {
    const int r = t & 31, q8 = t >> 5;
    float acc[JCAP];
#pragma unroll
    for (int j = 0; j < JCAP; ++j) acc[j] = 0.f;
#pragma unroll
    for (int c4 = 0; c4 < 4; ++c4) {
      const float4 uu = u4[(r << 5) + ((q8 * 4 + c4) ^ (r & 7))];
#pragma unroll
      for (int j = 0; j < JCAP; ++j) {
        const float4 vv = Vs4[j * 32 + q8 * 4 + c4];
        acc[j] += uu.x * vv.x + uu.y * vv.y + uu.z * vv.z + uu.w * vv.w;
      }
    }
    // lane l and l^32 hold the paired k-eighth -> k-quarter per wave
#pragma unroll
    for (int j = 0; j < JCAP; ++j) acc[j] += __shfl_xor(acc[j], 32, 64);
    if ((t & 32) == 0) {
      const int q4 = t >> 6;                        // wave id = k-quarter
#pragma unroll
      for (int j = 0; j < JCAP; ++j) PlCs[(q4 * JCAP + j) * TROW + r] = acc[j];
    }
  }
  __syncthreads();
  if (t < TROW) {                                   // softmax over j
    float lg[JCAP];
    float m = -1e30f;
#pragma unroll
    for (int j = 0; j < JCAP; ++j) {
      const float s = PlCs[j * TROW + t] + PlCs[(JCAP + j) * TROW + t]
                    + PlCs[(2 * JCAP + j) * TROW + t]
                    + PlCs[(3 * JCAP + j) * TROW + t];
      lg[j] = s; m = fmaxf(m, s);
    }
    float ss = 0.f;
#pragma unroll
    for (int j = 0; j < JCAP; ++j) { lg[j] = __expf(lg[j] - m); ss += lg[j]; }
    const float inv = 1.f / ss;
#pragma unroll
    for (int j = 0; j < JCAP; ++j) PlCs[j * TROW + t] = lg[j] * inv;  // Cs alias
  }
  __syncthreads();

  // phase 2: G[j][k] = sum_r c[j][r]*u[r][k]; wave owns j-subset; lane=k-pair
  {
    const int w = t >> 6, l = t & 63;
    const int j0 = (w < 2) ? 3 * w : 2 * w + 2;     // {0,3,6,8}
    const int jn = (w < 2) ? 3 : 2;                 // {3,3,2,2}
    const int chalf = l >> 1, cin = (l & 1) << 1;   // k = 2*l
    float g0[3], g1[3];
#pragma unroll
    for (int jj = 0; jj < 3; ++jj) { g0[jj] = 0.f; g1[jj] = 0.f; }
#pragma unroll
    for (int o = 0; o < 4; ++o) {                   // row octaves
      float ua[8], uc[8];
#pragma unroll
      for (int ri = 0; ri < 8; ++ri) {
        const int r = o * 8 + ri;
        const float2 uu2 =
            *(const float2*)((const float*)&u4[(r << 5) + (chalf ^ ri)] + cin);
        ua[ri] = uu2.x; uc[ri] = uu2.y;
      }
#pragma unroll
      for (int jj = 0; jj < 3; ++jj) {
        if (jj < jn) {
          const float4 cA = *(const float4*)&PlCs[(j0 + jj) * TROW + o * 8];
          const float4 cB = *(const float4*)&PlCs[(j0 + jj) * TROW + o * 8 + 4];
          g0[jj] += cA.x * ua[0] + cA.y * ua[1] + cA.z * ua[2] + cA.w * ua[3]
                  + cB.x * ua[4] + cB.y * ua[5] + cB.z * ua[6] + cB.w * ua[7];
          g1[jj] += cA.x * uc[0] + cA.y * uc[1] + cA.z * uc[2] + cA.w * uc[3]
                  + cB.x * uc[4] + cB.y * uc[5] + cB.z * uc[6] + cB.w * uc[7];
        }
      }
    }
    float* gb = Gp + ((size_t)(b * NT + tile)) * JCAP * KD;
#pragma unroll
    for (int jj = 0; jj < 3; ++jj)
      if (jj < jn)
        *(float2*)&gb[(j0 + jj) * KD + 2 * l] = make_float2(g0[jj], g1[jj]);
  }

  // ---- ticket: last block of batch b folds Gp -> {V (pass1) | out (pass2)} ----
  __threadfence();                       // each wave drains its own Gp stores
  __syncthreads();
  if (t == 0) isLast = (atomicAdd(&cnt[b], 1u) == NT - 1);
  __syncthreads();
  if (!isLast) return;
  __threadfence();                       // acquire: see all blocks' Gp
  float* gd  = (float*)Vs4;              // 1280 floats (Vs4 dead after ph1)
  float* o_s = PlCs;                     // 160 floats (PlCs dead after ph2)
  float* sc  = PlCs + JDIM;              // 10 floats
  {
    const float4* gp4 = (const float4*)(Gp + (size_t)(b * NT) * JCAP * KD);
    float4* gd4 = (float4*)gd;
#pragma unroll
    for (int i4 = t; i4 < JCAP * KD / 4; i4 += 256) {
      float4 s = make_float4(0.f, 0.f, 0.f, 0.f);
#pragma unroll 8
      for (int tl = 0; tl < NT; ++tl) {
        const float4 v = gp4[(size_t)tl * (JCAP * KD / 4) + i4];
        s.x += v.x; s.y += v.y; s.z += v.z; s.w += v.w;
      }
      gd4[i4] = s;
    }
  }
  __syncthreads();
  if (t < JDIM) {
    const int j = t >> 4;
    const float* gj = gd + j * KD;
    float a = 0.f;
#pragma unroll 8
    for (int k = 0; k < KD; ++k) a += gj[k] * W[k * JDIM + t];
    o_s[t] = a;
  }
  __syncthreads();
  if (pass == 1) {
    if (t < KD) {
      const float* wp = W + t * JDIM;
#pragma unroll
      for (int j = 0; j < JCAP; ++j) {
        float a = 0.f;
#pragma unroll
        for (int d = 0; d < DCAP; ++d) a += wp[j * DCAP + d] * o_s[j * DCAP + d];
        V[((size_t)(b * JCAP) + j) * KD + t] = a;
      }
    }
  } else {
    if (t < JCAP) {
      float s2 = 0.f;
#pragma unroll
      for (int d = 0; d < DCAP; ++d) { const float x = o_s[t * DCAP + d]; s2 += x * x; }
      sc[t] = s2 / ((1.f + s2) * sqrtf(s2 + EPSQ));
    }
    __syncthreads();
    if (t < JDIM) out[b * JDIM + t] = o_s[t] * sc[t >> 4];
  }
}

extern "C" void kernel_launch(void* const* d_in, const int* in_sizes, int n_in,
                              void* d_out, int out_size, void* d_ws, size_t ws_size,
                              hipStream_t stream) {
  const float* u = (const float*)d_in[0];   // (64,2048,128) fp32
  const float* W = (const float*)d_in[1];   // (128,160) fp32
  float* out = (float*)d_out;               // (64,10,16) fp32
  float* ws  = (float*)d_ws;

  hipMemsetAsync(d_ws, 0, 1024, stream);    // zero ticket counters
  f_iter0 <<<dim3(NT, BATCH), 256, 0, stream>>>(u, W, ws);
  f_route <<<dim3(NT, BATCH), 256, 0, stream>>>(u, W, ws, out, 1);
  f_route <<<dim3(NT, BATCH), 256, 0, stream>>>(u, W, ws, out, 2);
}